// Round 8
// baseline (135.172 us; speedup 1.0000x reference)
//
#include <hip/hip_runtime.h>
#include <math.h>

// Sizes (fixed by the problem)
#define B_ 8
#define C_ 64
#define T_ 16
#define H_ 56
#define W_ 56
#define HW_ (H_ * W_)   // 3136
#define CR_ 16

typedef __attribute__((ext_vector_type(8))) short bf16x8;
typedef __attribute__((ext_vector_type(4))) float f32x4;

// ---------------- helpers ----------------
__device__ __forceinline__ void atomicMaxF(float* addr, float v) {
    if (v >= 0.f) atomicMax((int*)addr, __float_as_int(v));
    else          atomicMin((unsigned int*)addr, (unsigned int)__float_as_int(v));
}

__device__ __forceinline__ unsigned short f2bf(float f) {
    unsigned u = __float_as_uint(f);
    u += 0x7fffu + ((u >> 16) & 1u);   // round to nearest even
    return (unsigned short)(u >> 16);
}

__device__ __forceinline__ void gload_lds16(const void* g, void* l) {
    __builtin_amdgcn_global_load_lds(
        (const __attribute__((address_space(1))) unsigned int*)g,
        (__attribute__((address_space(3))) unsigned int*)l,
        16, 0, 0);
}

// ---------------- K2b: prepack Wconv + init xt/pooled ----------------
__global__ __launch_bounds__(256) void prepack_kernel(
    const float* __restrict__ Wconv, float* __restrict__ packW0,
    float* __restrict__ pooled, float* __restrict__ xt)
{
    int idx = blockIdx.x * 256 + threadIdx.x;   // 144 blocks = 36864 threads
    if (idx < 512) pooled[idx] = -INFINITY;
    if (idx < 8192) xt[idx] = 0.f;
    if (idx >= 64 * 576) return;
    int j     = idx & 7;
    int lane  = (idx >> 3) & 63;
    int mt    = (idx >> 9) & 3;
    int kstep = idx >> 11;          // 0..17
    int cih = kstep & 1, tap = kstep >> 1;
    int co = mt * 16 + (lane & 15);
    int ci = cih * 32 + (lane >> 4) * 8 + j;
    packW0[idx] = Wconv[(co * C_ + ci) * 9 + tap];
}

// ---------------- K1: prep: xs = bf16(x+emb) + fused mean-pool -----------
// Grid: (bt, ch, g) = 128*8*7 = 7168 blocks, 128 threads.
// Thread = one item (row, 4-col group): 8 independent float4 loads, pack,
// 4 x 16B NONTEMPORAL stores (xs is stream-once data: keep x in L3, push
// xs straight to HBM -> avoid L3 pollution / x eviction).
// xs layout: [bt][ch][58 rows][58 cols][8 ci] bf16, zero borders.
// xt accumulated via atomicAdd (zeroed by prepack_kernel).
__global__ __launch_bounds__(128) void prep_kernel(
    const float* __restrict__ x, const float* __restrict__ emb,
    const int* __restrict__ viewp, unsigned short* __restrict__ xs,
    float* __restrict__ xt)
{
    __shared__ float sred[2][8];
    int blk = blockIdx.x;
    int g  = blk % 7;
    int ch = (blk / 7) & 7;
    int bt = blk / 56;
    int b = bt >> 4, t = bt & 15;
    int tid = threadIdx.x, lane = tid & 63, wv = tid >> 6;
    int view = viewp[0];

    float e[8];
    #pragma unroll
    for (int j = 0; j < 8; ++j) e[j] = emb[view * C_ + ch * 8 + j];

    const float* xb = x + ((size_t)(b * C_ + ch * 8) * T_ + t) * HW_;
    unsigned short* xso = xs + ((size_t)bt * 8 + ch) * (58 * 58) * 8;

    // borders handled by g==0 blocks: rows 0,57 + cols 0,57 of rows 1..56
    if (g == 0) {
        bf16x8 z8 = (bf16x8){0,0,0,0,0,0,0,0};
        for (int i = tid; i < 228; i += 128) {
            int r, c;
            if (i < 58)       { r = 0;            c = i; }
            else if (i < 116) { r = 57;           c = i - 58; }
            else if (i < 172) { r = i - 116 + 1;  c = 0; }
            else              { r = i - 172 + 1;  c = 57; }
            __builtin_nontemporal_store(z8, (bf16x8*)(xso + ((size_t)r * 58 + c) * 8));
        }
    }

    float psum[8];
    #pragma unroll
    for (int j = 0; j < 8; ++j) psum[j] = 0.f;

    // 112 items: row = 8g + i/14, cg = i%14 (thread i < 112)
    if (tid < 112) {
        int rl = tid / 14, cg = tid - rl * 14;
        int row = g * 8 + rl;
        int item = row * 14 + cg;                 // float4 index in plane
        float4 f[8];
        #pragma unroll
        for (int j = 0; j < 8; ++j) {
            float4 v = *(const float4*)(xb + (size_t)j * (T_ * HW_) + item * 4);
            v.x += e[j]; v.y += e[j]; v.z += e[j]; v.w += e[j];
            psum[j] = (v.x + v.y) + (v.z + v.w);
            f[j] = v;
        }
        unsigned short* outp = xso + ((size_t)(row + 1) * 58 + cg * 4 + 1) * 8;
        #pragma unroll
        for (int cc = 0; cc < 4; ++cc) {
            bf16x8 hv;
            #pragma unroll
            for (int j = 0; j < 8; ++j) {
                float comp = (cc == 0) ? f[j].x : (cc == 1) ? f[j].y
                           : (cc == 2) ? f[j].z : f[j].w;
                hv[j] = (short)f2bf(comp);
            }
            __builtin_nontemporal_store(hv, (bf16x8*)(outp + cc * 8));
        }
    }

    // block-partial mean-pool -> atomicAdd into xt[b, ch*8+j, t]
    #pragma unroll
    for (int j = 0; j < 8; ++j) {
        float s = psum[j];
        #pragma unroll
        for (int off = 32; off > 0; off >>= 1) s += __shfl_down(s, off);
        if (lane == 0) sred[wv][j] = s;
    }
    __syncthreads();
    if (tid < 8) {
        float s = sred[0][tid] + sred[1][tid];
        atomicAdd(&xt[((size_t)b * C_ + ch * 8 + tid) * T_ + t], s);
    }
}

// ---------------- K2: RouteFuncMLP -> alphaT[b,t,c] (LDS-staged) --------
__global__ __launch_bounds__(256) void route_kernel(
    const float* __restrict__ xt,
    const float* __restrict__ Wg, const float* __restrict__ bg,
    const float* __restrict__ Wa, const float* __restrict__ ba,
    const float* __restrict__ bng, const float* __restrict__ bnb,
    const float* __restrict__ bnm, const float* __restrict__ bnv,
    const float* __restrict__ Wb, float* __restrict__ alphaT)
{
    __shared__ float swg[64 * 65];   // Wg[c][i] at c*65+i (pad 65: no conflicts)
    __shared__ float swa[64 * 48];   // Wa[r][i][tap] at i*48 + r*3 + tap
    __shared__ float swb[48 * 64];   // Wb[c][r][tap] at (r*3+tap)*64 + c
    __shared__ float z[64 * 18];     // z[i][tslot], tslot = t+1 (0,17 = zero pad)
    __shared__ float gs[64], ggs[64];
    __shared__ float hs[16][18];     // hs[r][tslot]
    int b = blockIdx.x, tid = threadIdx.x;

    for (int idx = tid; idx < 4096; idx += 256) {
        int c = idx >> 6, i = idx & 63;
        swg[c * 65 + i] = Wg[idx];
    }
    for (int idx = tid; idx < 3072; idx += 256) {
        int r = idx / 192, rem = idx % 192;   // global Wa[r][i][tap]
        int i = rem / 3, tap = rem % 3;
        swa[i * 48 + r * 3 + tap] = Wa[idx];
    }
    for (int idx = tid; idx < 3072; idx += 256) {
        int k = idx >> 6, c = idx & 63;       // lds idx = k*64+c
        swb[idx] = Wb[c * 48 + k];
    }
    for (int idx = tid; idx < 1024; idx += 256) {
        int c = idx >> 4, t = idx & 15;
        z[c * 18 + t + 1] = xt[b * 1024 + idx] * (1.f / HW_);
    }
    if (tid < 64) { z[tid * 18] = 0.f; z[tid * 18 + 17] = 0.f; }
    if (tid < 16) { hs[tid][0] = 0.f; hs[tid][17] = 0.f; }
    __syncthreads();

    if (tid < 64) {
        float s = 0.f;
        #pragma unroll
        for (int t = 1; t <= 16; ++t) s += z[tid * 18 + t];
        gs[tid] = s * (1.f / 16.f);
    }
    __syncthreads();
    if (tid < 64) {
        float acc = bg[tid];
        #pragma unroll 8
        for (int i = 0; i < 64; ++i) acc = fmaf(swg[tid * 65 + i], gs[i], acc);
        ggs[tid] = acc;
    }
    __syncthreads();
    for (int idx = tid; idx < 1024; idx += 256) {
        int c = idx >> 4, t = idx & 15;
        z[c * 18 + t + 1] += ggs[c];
    }
    __syncthreads();

    // first conv (C->Cr) + BN + relu: one (r,t) per thread
    {
        int t = tid >> 4, r = tid & 15;
        float v = ba[r];
        #pragma unroll 8
        for (int i = 0; i < 64; ++i) {
            const float* wa = &swa[i * 48 + r * 3];
            const float* zz = &z[i * 18 + t];
            v = fmaf(zz[0], wa[0], v);
            v = fmaf(zz[1], wa[1], v);
            v = fmaf(zz[2], wa[2], v);
        }
        v = (v - bnm[r]) * rsqrtf(bnv[r] + 1e-5f);
        v = fmaf(v, bng[r], bnb[r]);
        hs[r][t + 1] = fmaxf(v, 0.f);
    }
    __syncthreads();

    // second conv (Cr->C), +1: idx = t*64 + c (coalesced LDS + global store)
    for (int idx = tid; idx < 1024; idx += 256) {
        int t = idx >> 6, c = idx & 63;
        float v = 1.f;
        #pragma unroll
        for (int r = 0; r < 16; ++r) {
            v = fmaf(hs[r][t],     swb[(r * 3 + 0) * 64 + c], v);
            v = fmaf(hs[r][t + 1], swb[(r * 3 + 1) * 64 + c], v);
            v = fmaf(hs[r][t + 2], swb[(r * 3 + 2) * 64 + c], v);
        }
        alphaT[(b * T_ + t) * C_ + c] = v;
    }
}

// ---------------- K2c: scale weights per (b,t) -> bf16 fragments -----
__global__ __launch_bounds__(256) void wscale_kernel(
    const float* __restrict__ packW0, const float* __restrict__ alphaT,
    unsigned short* __restrict__ packWbt)
{
    __shared__ float sal[C_];
    int bt = blockIdx.x, tid = threadIdx.x;
    if (tid < C_) sal[tid] = alphaT[bt * C_ + tid];
    __syncthreads();
    for (int f = tid; f < 4608; f += 256) {        // (kstep,mt,lane) frags
        int lane = f & 63, kstep = f >> 8;
        int cibase = (kstep & 1) * 32 + ((lane >> 4)) * 8;
        const float* w = packW0 + (size_t)f * 8;
        bf16x8 hv;
        #pragma unroll
        for (int j = 0; j < 8; ++j) hv[j] = (short)f2bf(w[j] * sal[cibase + j]);
        *(bf16x8*)(packWbt + (size_t)bt * 36864 + (size_t)f * 8) = hv;
    }
}

// ---------------- K3: conv (MFMA) + max-pool; split-ci staging ----------
// Block: one (b,t), 8-row strip, all 64 couts. 256 thr = 4 waves.
// ci split in 2 halves of 32 (4 chunks): stage half (37 KB LDS) -> 9 taps
// of MFMA -> barrier -> stage other half -> 9 taps. Occupancy 2 -> 3-4
// blocks/CU vs the 74 KB single-stage version.
// LDS: [stored_row 0..9][chunk 0..3][col 0..57][8 ci] bf16
#define RROWS 8
#define LROWS2 10
#define LCOLS2 58
#define HROWE (4 * LCOLS2)          // 232 bf16x8 per stored row (half)

__global__ __launch_bounds__(256) void conv_mfma_kernel(
    const unsigned short* __restrict__ xs,
    const unsigned short* __restrict__ packWbt,
    float* __restrict__ pooled)
{
    __shared__ bf16x8 ltile[LROWS2 * HROWE];    // 37120 B
    __shared__ float smax[4][C_];

    int blk = blockIdx.x;
    int strip = blk % 7;
    int bt = blk / 7;
    int b = bt >> 4;
    int h0 = strip * RROWS;
    int tid = threadIdx.x;
    int lane = tid & 63, wv = tid >> 6;
    int q = lane >> 4, li = lane & 15;

    const unsigned short* xsbt = xs + (size_t)bt * (8 * 3364 * 8);
    const bf16x8* pw = (const bf16x8*)(packWbt + (size_t)bt * 36864);

    int baddr[7];
    #pragma unroll
    for (int nt = 0; nt < 7; ++nt) {
        int p = (wv * 7 + nt) * 16 + li;
        int row = p / W_, col = p - row * W_;
        baddr[nt] = row * HROWE + q * LCOLS2 + col;
    }

    f32x4 acc[7][4];
    #pragma unroll
    for (int nt = 0; nt < 7; ++nt)
        #pragma unroll
        for (int mt = 0; mt < 4; ++mt)
            acc[nt][mt] = (f32x4){0.f, 0.f, 0.f, 0.f};

    #pragma unroll
    for (int half = 0; half < 2; ++half) {
        if (half) __syncthreads();   // WAR: all ds_reads of half 0 done
        // ---- stage 40 row-segments (10 rows x 4 chunks) of 58 x 16B ----
        for (int s = wv; s < 40; s += 4) {
            int row = s >> 2, ch = (s & 3) + half * 4;
            const unsigned short* src =
                xsbt + ((size_t)ch * 3364 + (size_t)(h0 + row) * 58 + lane) * 8;
            if (lane < 58)
                gload_lds16(src, &ltile[(row * 4 + (s & 3)) * LCOLS2]);
        }
        __syncthreads();             // drains vmcnt (gload_lds) too

        // ---- 9 taps x (4 mt x 7 nt) MFMA on this 32-ci half ----
        #pragma unroll
        for (int tap = 0; tap < 9; ++tap) {
            const int kh = tap / 3, kw = tap % 3;
            const int kstep = tap * 2 + half;
            const int boff = kh * HROWE + kw;
            bf16x8 af[4];
            #pragma unroll
            for (int mt = 0; mt < 4; ++mt)
                af[mt] = pw[(kstep * 4 + mt) * 64 + lane];
            #pragma unroll
            for (int nt = 0; nt < 7; ++nt) {
                bf16x8 bfr = ltile[baddr[nt] + boff];
                #pragma unroll
                for (int mt = 0; mt < 4; ++mt)
                    acc[nt][mt] = __builtin_amdgcn_mfma_f32_16x16x32_bf16(
                        af[mt], bfr, acc[nt][mt], 0, 0, 0);
            }
        }
    }

    // ---- fused max-pool ----
    float m[4][4];
    #pragma unroll
    for (int mt = 0; mt < 4; ++mt)
        #pragma unroll
        for (int i = 0; i < 4; ++i) {
            float v = acc[0][mt][i];
            #pragma unroll
            for (int nt = 1; nt < 7; ++nt) v = fmaxf(v, acc[nt][mt][i]);
            m[mt][i] = v;
        }
    #pragma unroll
    for (int off = 1; off < 16; off <<= 1)
        #pragma unroll
        for (int mt = 0; mt < 4; ++mt)
            #pragma unroll
            for (int i = 0; i < 4; ++i)
                m[mt][i] = fmaxf(m[mt][i], __shfl_xor(m[mt][i], off));
    if (li == 0) {
        #pragma unroll
        for (int mt = 0; mt < 4; ++mt)
            #pragma unroll
            for (int i = 0; i < 4; ++i)
                smax[wv][mt * 16 + q * 4 + i] = m[mt][i];
    }
    __syncthreads();
    if (tid < C_) {
        float mm = fmaxf(fmaxf(smax[0][tid], smax[1][tid]),
                         fmaxf(smax[2][tid], smax[3][tid]));
        atomicMaxF(&pooled[b * C_ + tid], mm);
    }
}

// ---------------- K4: classifier ----------------
__global__ void cls_kernel(const float* __restrict__ pooled,
                           const float* __restrict__ Wcls,
                           const float* __restrict__ bcls,
                           float* __restrict__ out)
{
    int i = threadIdx.x;
    if (i >= B_ * 10) return;
    int b = i / 10, k = i % 10;
    float v = bcls[k];
    for (int c = 0; c < C_; ++c) v = fmaf(pooled[b * C_ + c], Wcls[k * C_ + c], v);
    out[i] = v;
}

// ---------------- launcher ----------------
extern "C" void kernel_launch(void* const* d_in, const int* in_sizes, int n_in,
                              void* d_out, int out_size, void* d_ws, size_t ws_size,
                              hipStream_t stream)
{
    const float* x     = (const float*)d_in[0];
    const int*   view  = (const int*)  d_in[1];
    const float* emb   = (const float*)d_in[2];
    const float* Wg    = (const float*)d_in[3];
    const float* bg    = (const float*)d_in[4];
    const float* Wa    = (const float*)d_in[5];
    const float* ba    = (const float*)d_in[6];
    const float* bng   = (const float*)d_in[7];
    const float* bnb   = (const float*)d_in[8];
    const float* bnm   = (const float*)d_in[9];
    const float* bnv   = (const float*)d_in[10];
    const float* Wb    = (const float*)d_in[11];
    const float* Wconv = (const float*)d_in[12];
    const float* Wcls  = (const float*)d_in[13];
    const float* bcls  = (const float*)d_in[14];
    float* out = (float*)d_out;

    char* wsb = (char*)d_ws;
    float*          xt      = (float*)(wsb + 0);               // 32768 B
    float*          alphaT  = (float*)(wsb + 32768);           // 32768 B
    float*          pooled  = (float*)(wsb + 65536);           // 2048 B
    float*          packW0  = (float*)(wsb + 67584);           // 147456 B
    unsigned short* packWbt = (unsigned short*)(wsb + 215040); // 9437184 B
    unsigned short* xs      = (unsigned short*)(wsb + 9652224);// 55115776 B

    hipLaunchKernelGGL(prepack_kernel, dim3(144), dim3(256), 0, stream,
                       Wconv, packW0, pooled, xt);
    hipLaunchKernelGGL(prep_kernel, dim3(B_ * T_ * 8 * 7), dim3(128), 0, stream,
                       x, emb, view, xs, xt);
    hipLaunchKernelGGL(route_kernel, dim3(B_), dim3(256), 0, stream,
                       xt, Wg, bg, Wa, ba, bng, bnb, bnm, bnv, Wb, alphaT);
    hipLaunchKernelGGL(wscale_kernel, dim3(B_ * T_), dim3(256), 0, stream,
                       packW0, alphaT, packWbt);
    hipLaunchKernelGGL(conv_mfma_kernel, dim3(B_ * T_ * 7), dim3(256), 0, stream,
                       xs, packWbt, pooled);
    hipLaunchKernelGGL(cls_kernel, dim3(1), dim3(128), 0, stream, pooled, Wcls, bcls, out);
}

// Round 9
// 87.489 us; speedup vs baseline: 1.5450x; 1.5450x over previous
//
#include <hip/hip_runtime.h>
#include <math.h>

// Sizes (fixed by the problem)
#define B_ 8
#define C_ 64
#define T_ 16
#define H_ 56
#define W_ 56
#define HW_ (H_ * W_)   // 3136
#define CR_ 16
#define PLANE (T_ * HW_)   // 50176 floats per (b,c) plane

typedef __attribute__((ext_vector_type(8))) short bf16x8;
typedef __attribute__((ext_vector_type(4))) float f32x4;

// ---------------- helpers ----------------
__device__ __forceinline__ void atomicMaxF(float* addr, float v) {
    if (v >= 0.f) atomicMax((int*)addr, __float_as_int(v));
    else          atomicMin((unsigned int*)addr, (unsigned int)__float_as_int(v));
}

__device__ __forceinline__ unsigned short f2bf(float f) {
    unsigned u = __float_as_uint(f);
    u += 0x7fffu + ((u >> 16) & 1u);   // round to nearest even
    return (unsigned short)(u >> 16);
}

// ---------------- K0: prepack Wconv -> bf16 fragments + init pooled ------
// packWbf element idx = ((kstep*4 + mtile)*64 + lane)*8 + j
//   kstep = tap*2 + cih ; co = mtile*16 + (lane&15)
//   ci = cih*32 + (lane>>4)*8 + j ; tap = kh*3+kw
__global__ __launch_bounds__(256) void prepack_kernel(
    const float* __restrict__ Wconv, unsigned short* __restrict__ packWbf,
    float* __restrict__ pooled)
{
    int idx = blockIdx.x * 256 + threadIdx.x;   // 144 blocks = 36864 threads
    if (idx < 512) pooled[idx] = -INFINITY;
    if (idx >= 64 * 576) return;
    int j     = idx & 7;
    int lane  = (idx >> 3) & 63;
    int mt    = (idx >> 9) & 3;
    int kstep = idx >> 11;          // 0..17
    int cih = kstep & 1, tap = kstep >> 1;
    int co = mt * 16 + (lane & 15);
    int ci = cih * 32 + (lane >> 4) * 8 + j;
    packWbf[idx] = f2bf(Wconv[(co * C_ + ci) * 9 + tap]);
}

// ---------------- K1: pool: xt[b,c,t] = sum over HW of x ----------------
// Pure linear read of x (103 MB), one block per (b,c,t) plane-slice.
__global__ __launch_bounds__(128) void pool_kernel(
    const float* __restrict__ x, float* __restrict__ xt)
{
    __shared__ float red[2];
    int bct = blockIdx.x;           // ((b*64+c)*16+t), 8192 blocks
    const float4* p = (const float4*)(x + (size_t)bct * HW_);
    int tid = threadIdx.x;
    float s = 0.f;
    #pragma unroll
    for (int k = 0; k < 7; ++k) {
        int i = tid + k * 128;
        if (i < 784) { float4 v = p[i]; s += (v.x + v.y) + (v.z + v.w); }
    }
    #pragma unroll
    for (int off = 32; off > 0; off >>= 1) s += __shfl_down(s, off);
    if ((tid & 63) == 0) red[tid >> 6] = s;
    __syncthreads();
    if (tid == 0) xt[bct] = red[0] + red[1];
}

// ---------------- K2: RouteFuncMLP -> alphaT[b,t,c] (LDS-staged) --------
__global__ __launch_bounds__(256) void route_kernel(
    const float* __restrict__ xt, const float* __restrict__ emb,
    const int* __restrict__ viewp,
    const float* __restrict__ Wg, const float* __restrict__ bg,
    const float* __restrict__ Wa, const float* __restrict__ ba,
    const float* __restrict__ bng, const float* __restrict__ bnb,
    const float* __restrict__ bnm, const float* __restrict__ bnv,
    const float* __restrict__ Wb, float* __restrict__ alphaT)
{
    __shared__ float swg[64 * 65];   // Wg[c][i] at c*65+i (pad 65: no conflicts)
    __shared__ float swa[64 * 48];   // Wa[r][i][tap] at i*48 + r*3 + tap
    __shared__ float swb[48 * 64];   // Wb[c][r][tap] at (r*3+tap)*64 + c
    __shared__ float z[64 * 18];     // z[i][tslot], tslot = t+1 (0,17 = zero pad)
    __shared__ float gs[64], ggs[64], sge[64];
    __shared__ float hs[16][18];     // hs[r][tslot]
    int b = blockIdx.x, tid = threadIdx.x;

    if (tid < 64) sge[tid] = emb[viewp[0] * C_ + tid];
    for (int idx = tid; idx < 4096; idx += 256) {
        int c = idx >> 6, i = idx & 63;
        swg[c * 65 + i] = Wg[idx];
    }
    for (int idx = tid; idx < 3072; idx += 256) {
        int r = idx / 192, rem = idx % 192;   // global Wa[r][i][tap]
        int i = rem / 3, tap = rem % 3;
        swa[i * 48 + r * 3 + tap] = Wa[idx];
    }
    for (int idx = tid; idx < 3072; idx += 256) {
        int k = idx >> 6, c = idx & 63;       // lds idx = k*64+c
        swb[idx] = Wb[c * 48 + k];
    }
    if (tid < 64) { z[tid * 18] = 0.f; z[tid * 18 + 17] = 0.f; }
    if (tid < 16) { hs[tid][0] = 0.f; hs[tid][17] = 0.f; }
    __syncthreads();   // sge ready
    for (int idx = tid; idx < 1024; idx += 256) {
        int c = idx >> 4, t = idx & 15;
        z[c * 18 + t + 1] = xt[b * 1024 + idx] * (1.f / HW_) + sge[c];
    }
    __syncthreads();

    if (tid < 64) {
        float s = 0.f;
        #pragma unroll
        for (int t = 1; t <= 16; ++t) s += z[tid * 18 + t];
        gs[tid] = s * (1.f / 16.f);
    }
    __syncthreads();
    if (tid < 64) {
        float acc = bg[tid];
        #pragma unroll 8
        for (int i = 0; i < 64; ++i) acc = fmaf(swg[tid * 65 + i], gs[i], acc);
        ggs[tid] = acc;
    }
    __syncthreads();
    for (int idx = tid; idx < 1024; idx += 256) {
        int c = idx >> 4, t = idx & 15;
        z[c * 18 + t + 1] += ggs[c];
    }
    __syncthreads();

    // first conv (C->Cr) + BN + relu: one (r,t) per thread
    {
        int t = tid >> 4, r = tid & 15;
        float v = ba[r];
        #pragma unroll 8
        for (int i = 0; i < 64; ++i) {
            const float* wa = &swa[i * 48 + r * 3];
            const float* zz = &z[i * 18 + t];
            v = fmaf(zz[0], wa[0], v);
            v = fmaf(zz[1], wa[1], v);
            v = fmaf(zz[2], wa[2], v);
        }
        v = (v - bnm[r]) * rsqrtf(bnv[r] + 1e-5f);
        v = fmaf(v, bng[r], bnb[r]);
        hs[r][t + 1] = fmaxf(v, 0.f);
    }
    __syncthreads();

    // second conv (Cr->C), +1: idx = t*64 + c (coalesced LDS + global store)
    for (int idx = tid; idx < 1024; idx += 256) {
        int t = idx >> 6, c = idx & 63;
        float v = 1.f;
        #pragma unroll
        for (int r = 0; r < 16; ++r) {
            v = fmaf(hs[r][t],     swb[(r * 3 + 0) * 64 + c], v);
            v = fmaf(hs[r][t + 1], swb[(r * 3 + 1) * 64 + c], v);
            v = fmaf(hs[r][t + 2], swb[(r * 3 + 2) * 64 + c], v);
        }
        alphaT[(b * T_ + t) * C_ + c] = v;
    }
}

// ---------------- K3: fused scale+conv (MFMA) + max-pool -----------------
// Reads x DIRECTLY (no xs intermediate). Block: one (b,t), 8-row strip,
// all 64 couts, 256 thr = 4 waves. alpha applied to input during pack:
// (x+e)*a = x*a + e*a. ci split in 2 halves of 32: stage half into 37 KB
// LDS ([row 0..9][ch4 0..3][col 0..57][8ci] bf16), 9 taps MFMA, repeat.
#define LCOLS2 58
#define HROWE (4 * LCOLS2)          // 232 bf16x8 per stored row (half)

__global__ __launch_bounds__(256) void conv_mfma_kernel(
    const float* __restrict__ x, const float* __restrict__ emb,
    const int* __restrict__ viewp, const float* __restrict__ alphaT,
    const unsigned short* __restrict__ packWbf, float* __restrict__ pooled)
{
    __shared__ bf16x8 ltile[10 * HROWE];    // 37120 B
    __shared__ float sa[C_], sea[C_];
    __shared__ float smax[4][C_];

    int blk = blockIdx.x;
    int strip = blk % 7;
    int bt = blk / 7;
    int b = bt >> 4, t = bt & 15;
    int h0 = strip * 8;
    int tid = threadIdx.x;
    int lane = tid & 63, wv = tid >> 6;
    int q = lane >> 4, li = lane & 15;

    if (tid < C_) {
        float a = alphaT[bt * C_ + tid];
        sa[tid] = a;
        sea[tid] = emb[viewp[0] * C_ + tid] * a;
    }
    // zero border cols 0,57 once (never touched by interior staging)
    if (tid >= 64 && tid < 144) {
        int i = tid - 64;            // 0..79 = 10 rows x 4 ch x 2 sides
        int r = i / 8, c8 = i - r * 8;
        int ch4 = c8 >> 1, col = (c8 & 1) ? 57 : 0;
        ltile[(r * 4 + ch4) * LCOLS2 + col] = (bf16x8){0,0,0,0,0,0,0,0};
    }

    const float* xb = x + ((size_t)(b * C_) * T_ + t) * HW_;   // + ci*PLANE

    int baddr[7];
    #pragma unroll
    for (int nt = 0; nt < 7; ++nt) {
        int p = (wv * 7 + nt) * 16 + li;
        int row = p / W_, col = p - row * W_;
        baddr[nt] = row * HROWE + q * LCOLS2 + col;
    }

    f32x4 acc[7][4];
    #pragma unroll
    for (int nt = 0; nt < 7; ++nt)
        #pragma unroll
        for (int mt = 0; mt < 4; ++mt)
            acc[nt][mt] = (f32x4){0.f, 0.f, 0.f, 0.f};

    const bf16x8* pw = (const bf16x8*)packWbf;

    #pragma unroll
    for (int half = 0; half < 2; ++half) {
        __syncthreads();   // half 0: sa/sea/border ready; half 1: WAR on ltile
        // ---- stage 560 items (4 ch4 x 10 rows x 14 colquads) from x ----
        #pragma unroll
        for (int k = 0; k < 3; ++k) {
            int item = tid + k * 256;
            if (item < 560) {
                int ch4 = item / 140;
                int rem = item - ch4 * 140;
                int row = rem / 14, cq = rem - row * 14;
                int gr = h0 - 1 + row;
                int ci0 = half * 32 + ch4 * 8;
                bf16x8 hv[4] = {(bf16x8){0,0,0,0,0,0,0,0}, (bf16x8){0,0,0,0,0,0,0,0},
                                (bf16x8){0,0,0,0,0,0,0,0}, (bf16x8){0,0,0,0,0,0,0,0}};
                if ((unsigned)gr < (unsigned)H_) {
                    const float* src = xb + (size_t)ci0 * PLANE + gr * W_ + cq * 4;
                    float4 f[8];
                    #pragma unroll
                    for (int j = 0; j < 8; ++j)
                        f[j] = *(const float4*)(src + (size_t)j * PLANE);
                    #pragma unroll
                    for (int j = 0; j < 8; ++j) {
                        float aj = sa[ci0 + j], ej = sea[ci0 + j];
                        hv[0][j] = (short)f2bf(fmaf(f[j].x, aj, ej));
                        hv[1][j] = (short)f2bf(fmaf(f[j].y, aj, ej));
                        hv[2][j] = (short)f2bf(fmaf(f[j].z, aj, ej));
                        hv[3][j] = (short)f2bf(fmaf(f[j].w, aj, ej));
                    }
                }
                bf16x8* dst = &ltile[(row * 4 + ch4) * LCOLS2 + cq * 4 + 1];
                #pragma unroll
                for (int cc = 0; cc < 4; ++cc) dst[cc] = hv[cc];
            }
        }
        __syncthreads();

        // ---- 9 taps x (4 mt x 7 nt) MFMA on this 32-ci half ----
        #pragma unroll
        for (int tap = 0; tap < 9; ++tap) {
            const int kh = tap / 3, kw = tap % 3;
            const int kstep = tap * 2 + half;
            const int boff = kh * HROWE + kw;
            bf16x8 af[4];
            #pragma unroll
            for (int mt = 0; mt < 4; ++mt)
                af[mt] = pw[(kstep * 4 + mt) * 64 + lane];
            #pragma unroll
            for (int nt = 0; nt < 7; ++nt) {
                bf16x8 bfr = ltile[baddr[nt] + boff];
                #pragma unroll
                for (int mt = 0; mt < 4; ++mt)
                    acc[nt][mt] = __builtin_amdgcn_mfma_f32_16x16x32_bf16(
                        af[mt], bfr, acc[nt][mt], 0, 0, 0);
            }
        }
    }

    // ---- fused max-pool ----
    float m[4][4];
    #pragma unroll
    for (int mt = 0; mt < 4; ++mt)
        #pragma unroll
        for (int i = 0; i < 4; ++i) {
            float v = acc[0][mt][i];
            #pragma unroll
            for (int nt = 1; nt < 7; ++nt) v = fmaxf(v, acc[nt][mt][i]);
            m[mt][i] = v;
        }
    #pragma unroll
    for (int off = 1; off < 16; off <<= 1)
        #pragma unroll
        for (int mt = 0; mt < 4; ++mt)
            #pragma unroll
            for (int i = 0; i < 4; ++i)
                m[mt][i] = fmaxf(m[mt][i], __shfl_xor(m[mt][i], off));
    if (li == 0) {
        #pragma unroll
        for (int mt = 0; mt < 4; ++mt)
            #pragma unroll
            for (int i = 0; i < 4; ++i)
                smax[wv][mt * 16 + q * 4 + i] = m[mt][i];
    }
    __syncthreads();
    if (tid < C_) {
        float mm = fmaxf(fmaxf(smax[0][tid], smax[1][tid]),
                         fmaxf(smax[2][tid], smax[3][tid]));
        atomicMaxF(&pooled[b * C_ + tid], mm);
    }
}

// ---------------- K4: classifier ----------------
__global__ void cls_kernel(const float* __restrict__ pooled,
                           const float* __restrict__ Wcls,
                           const float* __restrict__ bcls,
                           float* __restrict__ out)
{
    int i = threadIdx.x;
    if (i >= B_ * 10) return;
    int b = i / 10, k = i % 10;
    float v = bcls[k];
    for (int c = 0; c < C_; ++c) v = fmaf(pooled[b * C_ + c], Wcls[k * C_ + c], v);
    out[i] = v;
}

// ---------------- launcher ----------------
extern "C" void kernel_launch(void* const* d_in, const int* in_sizes, int n_in,
                              void* d_out, int out_size, void* d_ws, size_t ws_size,
                              hipStream_t stream)
{
    const float* x     = (const float*)d_in[0];
    const int*   view  = (const int*)  d_in[1];
    const float* emb   = (const float*)d_in[2];
    const float* Wg    = (const float*)d_in[3];
    const float* bg    = (const float*)d_in[4];
    const float* Wa    = (const float*)d_in[5];
    const float* ba    = (const float*)d_in[6];
    const float* bng   = (const float*)d_in[7];
    const float* bnb   = (const float*)d_in[8];
    const float* bnm   = (const float*)d_in[9];
    const float* bnv   = (const float*)d_in[10];
    const float* Wb    = (const float*)d_in[11];
    const float* Wconv = (const float*)d_in[12];
    const float* Wcls  = (const float*)d_in[13];
    const float* bcls  = (const float*)d_in[14];
    float* out = (float*)d_out;

    char* wsb = (char*)d_ws;
    float*          xt      = (float*)(wsb + 0);               // 32768 B
    float*          alphaT  = (float*)(wsb + 32768);           // 32768 B
    float*          pooled  = (float*)(wsb + 65536);           // 2048 B
    unsigned short* packWbf = (unsigned short*)(wsb + 67584);  // 73728 B

    hipLaunchKernelGGL(prepack_kernel, dim3(144), dim3(256), 0, stream,
                       Wconv, packWbf, pooled);
    hipLaunchKernelGGL(pool_kernel, dim3(B_ * C_ * T_), dim3(128), 0, stream,
                       x, xt);
    hipLaunchKernelGGL(route_kernel, dim3(B_), dim3(256), 0, stream,
                       xt, emb, view, Wg, bg, Wa, ba, bng, bnb, bnm, bnv, Wb, alphaT);
    hipLaunchKernelGGL(conv_mfma_kernel, dim3(B_ * T_ * 7), dim3(256), 0, stream,
                       x, emb, view, alphaT, packWbf, pooled);
    hipLaunchKernelGGL(cls_kernel, dim3(1), dim3(128), 0, stream, pooled, Wcls, bcls, out);
}